// Round 23
// baseline (126.465 us; speedup 1.0000x reference)
//
#include <hip/hip_runtime.h>
#include <stdint.h>

// VectorQuantizer — f32 I/O confirmed. d_in[0]=z [16384,64], d_in[1]=e [8192,64];
// d_out f32: [z_q 16384*64][idx-as-float 16384]. d_ws = 256MB confirmed.
//
// FROZEN exact numerics (eval path only):
//   sz,se: scalar pairwise-8; c: 4 lanes (k mod 4), mul/add separately rounded,
//   16-chunks ascending, reversed sub-blocks (+12,+8,+4,+0), hadd (q0+q1)+(q2+q3);
//   A=fl(sz+se); d=fl(A-2c); argmin strict-<, first (smallest) index wins.
//
// Round-23: eval v14 — ZERO LDS. Occupancy record r13-r22 fits a ~64KB
// schedulable-LDS pool (34.8KB tile -> 1 block/CU -> Occ 15% -> 1024 blocks in
// ~4 serial layers = the stubborn ~40us). Fix: drop e-LDS; read e from the
// transposed f32 copy e_t[64][8192] (r9-verified transpose): per k-granule,
// lane reads e_t[k][ch*128+2*lane] float2 = 512B/wave coalesced, L2-resident.
// z stays lane-distributed + compile-time readlane (v10). No LDS, no barriers
// -> 8 blocks/CU, all 1024 blocks co-resident. Frozen order preserved; lane
// owns j=2l,2l+1 (ascending); verified atomicMin combine; dup-tail idempotent.

#define NROWS 16384
#define NE    8192
#define D     64
#define BN    128
#define NCH   (NE / BN)     // 64
#define BAND  1.25e-4f
#define CAND_CAP 16384
#define EVG   16            // item-groups per chunk

typedef __attribute__((ext_vector_type(8))) short short8;
typedef __attribute__((ext_vector_type(4))) float f32x4;

__device__ __forceinline__ uint32_t bf16rn(float f) {
    union { float f; uint32_t u; } c; c.f = f;
    return (c.u + 0x7FFFu + ((c.u >> 16) & 1u)) >> 16;
}
__device__ __forceinline__ uint32_t pk2(float lo, float hi) {
    return bf16rn(lo) | (bf16rn(hi) << 16);
}
#define RL(v, l) __uint_as_float(__builtin_amdgcn_readlane(__float_as_uint(v), (l)))

// ---------- phase 0a: fused convert + coalesced exact prep (verified) ----------
__global__ __launch_bounds__(256)
void vq_convert_prep(const float* __restrict__ z, const float* __restrict__ e,
                     uint32_t* __restrict__ zb, uint32_t* __restrict__ eb,
                     float* __restrict__ sz_arr, float* __restrict__ se_arr)
{
    if (blockIdx.x < 768) {
        const int i = blockIdx.x * 256 + threadIdx.x;
        const int nz = NROWS * D / 8;
        const int ne = NE * D / 8;
        if (i < nz) {
            const float4 a = ((const float4*)z)[i * 2];
            const float4 b = ((const float4*)z)[i * 2 + 1];
            uint4 o; o.x = pk2(a.x, a.y); o.y = pk2(a.z, a.w);
            o.z = pk2(b.x, b.y); o.w = pk2(b.z, b.w);
            ((uint4*)zb)[i] = o;
        } else if (i < nz + ne) {
            const int k = i - nz;
            const float4 a = ((const float4*)e)[k * 2];
            const float4 b = ((const float4*)e)[k * 2 + 1];
            uint4 o; o.x = pk2(a.x, a.y); o.y = pk2(a.z, a.w);
            o.z = pk2(b.x, b.y); o.w = pk2(b.z, b.w);
            ((uint4*)eb)[k] = o;
        }
    } else {
        const int pb   = blockIdx.x - 768;
        const int wave = threadIdx.x >> 6, lane = threadIdx.x & 63;
        const int g    = lane & 7;
        const int grow = pb * 32 + wave * 8 + (lane >> 3);
        const float* src = (grow < NROWS) ? z + (size_t)grow * D
                                          : e + (size_t)(grow - NROWS) * D;
        float acc = 0.f;
        #pragma unroll
        for (int i = 0; i < 8; ++i) {
            const float x = src[i * 8 + g];
            acc = __fadd_rn(acc, __fmul_rn(x, x));
        }
        const float s1 = __fadd_rn(acc, __shfl_xor(acc, 1, 64));
        const float s2 = __fadd_rn(s1,  __shfl_xor(s1, 2, 64));
        const float s4 = __fadd_rn(s2,  __shfl_xor(s2, 4, 64));
        if (g == 0) {
            if (grow < NROWS) sz_arr[grow] = s4;
            else              se_arr[grow - NROWS] = s4;
        }
    }
}

// ---------- phase 0b: e [8192][64] -> e_t [64][8192] (r9-verified) ----------
__global__ __launch_bounds__(256)
void vq_transpose(const float* __restrict__ e, float* __restrict__ et)
{
    __shared__ float tile[64][65];
    const int t  = threadIdx.x;
    const int j0 = blockIdx.x * 64;
    const int r  = t >> 4;        // 0..15
    const int c4 = t & 15;        // 0..15

    #pragma unroll
    for (int rr = 0; rr < 4; ++rr) {
        const int row = rr * 16 + r;
        const float4 v = *(const float4*)(e + (size_t)(j0 + row) * D + c4 * 4);
        tile[row][c4 * 4 + 0] = v.x; tile[row][c4 * 4 + 1] = v.y;
        tile[row][c4 * 4 + 2] = v.z; tile[row][c4 * 4 + 3] = v.w;
    }
    __syncthreads();
    #pragma unroll
    for (int rr = 0; rr < 4; ++rr) {
        const int k = rr * 16 + r;
        float4 o;
        o.x = tile[c4 * 4 + 0][k]; o.y = tile[c4 * 4 + 1][k];
        o.z = tile[c4 * 4 + 2][k]; o.w = tile[c4 * 4 + 3][k];
        *(float4*)(et + (size_t)k * NE + j0 + c4 * 4) = o;
    }
}

// ---------- phase 1: scan v2 (r22) — one chunk/block, shfl-max reduce ----------
__global__ __launch_bounds__(256)
void vq_scan_mfma(const uint16_t* __restrict__ zb, const uint16_t* __restrict__ eb,
                  float* __restrict__ cmax)
{
    __shared__ uint16_t elds[BN][72];

    const int tid  = threadIdx.x;
    const int lane = tid & 63, w = tid >> 6;
    const int mb   = blockIdx.x >> 6;
    const int ch   = blockIdx.x & 63;
    const int row0 = mb * 256 + w * 64;
    const int l15  = lane & 15, l4 = lane >> 4;

    {
        const int srow = tid >> 1, shalf = tid & 1;
        const uint16_t* sp = eb + (size_t)(ch * BN + srow) * D + shalf * 32;
        uint16_t* dp = &elds[srow][shalf * 32];
        #pragma unroll
        for (int q = 0; q < 4; ++q)
            *(short8*)(dp + q * 8) = *(const short8*)(sp + q * 8);
    }

    short8 af[4][2];
    #pragma unroll
    for (int m = 0; m < 4; ++m)
        #pragma unroll
        for (int h = 0; h < 2; ++h)
            af[m][h] = *(const short8*)(zb + (size_t)(row0 + m * 16 + l15) * D + h * 32 + l4 * 8);

    __syncthreads();

    const f32x4 z4 = {0.f, 0.f, 0.f, 0.f};
    f32x4 rm[4];
    #pragma unroll
    for (int m = 0; m < 4; ++m) rm[m] = {-3.0e38f, -3.0e38f, -3.0e38f, -3.0e38f};

    #pragma unroll 1
    for (int n = 0; n < 8; ++n) {
        const uint16_t* bp = &elds[n * 16 + l15][l4 * 8];
        const short8 b0 = *(const short8*)(bp);
        const short8 b1 = *(const short8*)(bp + 32);
        #pragma unroll
        for (int m = 0; m < 4; ++m) {
            f32x4 acc = __builtin_amdgcn_mfma_f32_16x16x32_bf16(af[m][0], b0, z4, 0, 0, 0);
            acc = __builtin_amdgcn_mfma_f32_16x16x32_bf16(af[m][1], b1, acc, 0, 0, 0);
            #pragma unroll
            for (int r = 0; r < 4; ++r) rm[m][r] = fmaxf(rm[m][r], acc[r]);
        }
    }

    #pragma unroll
    for (int m = 0; m < 4; ++m) {
        #pragma unroll
        for (int r = 0; r < 4; ++r) {
            #pragma unroll
            for (int o = 1; o < 16; o <<= 1)
                rm[m][r] = fmaxf(rm[m][r], __shfl_xor(rm[m][r], o, 64));
        }
        if (l15 < 4) {
            const float v = (l15 == 0) ? rm[m][0] : (l15 == 1) ? rm[m][1]
                          : (l15 == 2) ? rm[m][2] : rm[m][3];
            cmax[(size_t)(row0 + m * 16 + l4 * 4 + l15) * NCH + ch] = v;
        }
    }
}

// ---------- phase 2a: band-select -> per-row bitmask (no atomics) ----------
__global__ __launch_bounds__(256)
void vq_select_mask(const float* __restrict__ cmax,
                    unsigned long long* __restrict__ mask,
                    unsigned long long* __restrict__ packed)
{
    const int lane = threadIdx.x & 63, w = threadIdx.x >> 6;
    const int row = blockIdx.x * 4 + w;

    const float ci = cmax[(size_t)row * NCH + lane];
    float cm = ci;
    #pragma unroll
    for (int o = 1; o < 64; o <<= 1) cm = fmaxf(cm, __shfl_xor(cm, o, 64));
    const unsigned long long m = __ballot(ci >= cm - BAND);
    if (lane == 0) { mask[row] = m; packed[row] = 0xFFFFFFFFFFFFFFFFull; }
}

// ---------- phase 2b: compaction (barrier-free, LDS atomic, unordered) ----------
__global__ __launch_bounds__(256)
void vq_compact(const unsigned long long* __restrict__ mask,
                int* __restrict__ cand, unsigned int* __restrict__ counts)
{
    __shared__ unsigned int cnt_lds;
    const int ch = blockIdx.x;
    const int t = threadIdx.x, lane = t & 63;
    if (t == 0) cnt_lds = 0;
    __syncthreads();

    #pragma unroll 1
    for (int r0 = 0; r0 < NROWS; r0 += 256) {
        const int row = r0 + t;
        const bool hit = (mask[row] >> ch) & 1ull;
        const unsigned long long b = __ballot(hit);
        unsigned int base = 0;
        if (lane == 0 && b) base = atomicAdd(&cnt_lds, (unsigned int)__popcll(b));
        base = (unsigned int)__shfl((int)base, 0, 64);
        if (hit) {
            const unsigned int rank = (unsigned int)__popcll(b & ((1ull << lane) - 1ull));
            cand[(size_t)ch * CAND_CAP + base + rank] = row;
        }
    }
    __syncthreads();
    if (t == 0) counts[ch] = cnt_lds;
}

// ---------- phase 2c: eval v14 — zero LDS, e via transposed coalesced reads ----------
__global__ __launch_bounds__(256)
void vq_eval(const float* __restrict__ z, const float* __restrict__ et,
             const float* __restrict__ sz_arr, const float* __restrict__ se_arr,
             const unsigned int* __restrict__ counts, const int* __restrict__ cand,
             unsigned long long* __restrict__ packed)
{
    const int ch  = blockIdx.x;          // 0..63
    const int grp = blockIdx.y;          // 0..EVG-1
    const int t   = threadIdx.x, lane = t & 63, w = t >> 6;

    const unsigned int cnt = counts[ch];
    const int base0 = grp * 16;
    if ((unsigned int)base0 >= cnt) return;

    const int jcol = ch * BN + 2 * lane;          // this lane's j-pair: jcol, jcol+1
    const float2 se2 = *(const float2*)(se_arr + jcol);   // coalesced
    const int gsrc  = lane & 15;                  // granule this lane sources
    const int isrc  = lane >> 4;                  // item this lane sources (0..3)

    for (unsigned int s0 = (unsigned int)(base0 + w * 4); s0 < cnt; s0 += (unsigned int)EVG * 16u) {
        int rows[4]; float szs[4];
        #pragma unroll
        for (int it = 0; it < 4; ++it) {
            unsigned int si = s0 + it; if (si >= cnt) si = cnt - 1;   // dup: idempotent
            rows[it] = cand[(size_t)ch * CAND_CAP + si];   // uniform -> s_load
            szs[it]  = sz_arr[rows[it]];                   // uniform -> s_load
        }
        // lane-distributed z: lane holds granule gsrc of item isrc (one float4 load)
        const float4 zf = *(const float4*)(z + (size_t)rows[isrc] * D + gsrc * 4);

        float acc[4][2][4];   // [item][jpair][q]
        #pragma unroll
        for (int it = 0; it < 4; ++it)
            #pragma unroll
            for (int jr = 0; jr < 2; ++jr)
                #pragma unroll
                for (int q = 0; q < 4; ++q) acc[it][jr][q] = 0.f;

        // frozen order: cc ascending; granules +12,+8,+4,+0; q_i gets k===i mod 4.
        // e via e_t rows: per k, wave reads 512B contiguous (L2-resident, no LDS).
        #pragma unroll
        for (int cc = 0; cc < 4; ++cc) {
            #pragma unroll
            for (int sb = 3; sb >= 0; --sb) {
                const int b = cc * 16 + sb * 4;
                const int g = cc * 4 + sb;
                const float2 e0 = *(const float2*)(et + (size_t)(b + 0) * NE + jcol);
                const float2 e1 = *(const float2*)(et + (size_t)(b + 1) * NE + jcol);
                const float2 e2 = *(const float2*)(et + (size_t)(b + 2) * NE + jcol);
                const float2 e3 = *(const float2*)(et + (size_t)(b + 3) * NE + jcol);
                #pragma unroll
                for (int it = 0; it < 4; ++it) {
                    const int sl = it * 16 + g;            // compile-time lane
                    const float z0 = RL(zf.x, sl);
                    const float z1 = RL(zf.y, sl);
                    const float z2 = RL(zf.z, sl);
                    const float z3 = RL(zf.w, sl);
                    acc[it][0][0] = __fadd_rn(acc[it][0][0], __fmul_rn(z0, e0.x));
                    acc[it][0][1] = __fadd_rn(acc[it][0][1], __fmul_rn(z1, e1.x));
                    acc[it][0][2] = __fadd_rn(acc[it][0][2], __fmul_rn(z2, e2.x));
                    acc[it][0][3] = __fadd_rn(acc[it][0][3], __fmul_rn(z3, e3.x));
                    acc[it][1][0] = __fadd_rn(acc[it][1][0], __fmul_rn(z0, e0.y));
                    acc[it][1][1] = __fadd_rn(acc[it][1][1], __fmul_rn(z1, e1.y));
                    acc[it][1][2] = __fadd_rn(acc[it][1][2], __fmul_rn(z2, e2.y));
                    acc[it][1][3] = __fadd_rn(acc[it][1][3], __fmul_rn(z3, e3.y));
                }
            }
        }

        #pragma unroll
        for (int it = 0; it < 4; ++it) {
            const float c0 = __fadd_rn(__fadd_rn(acc[it][0][0], acc[it][0][1]),
                                       __fadd_rn(acc[it][0][2], acc[it][0][3]));
            const float c1 = __fadd_rn(__fadd_rn(acc[it][1][0], acc[it][1][1]),
                                       __fadd_rn(acc[it][1][2], acc[it][1][3]));
            const float A0 = __fadd_rn(szs[it], se2.x);
            const float A1 = __fadd_rn(szs[it], se2.y);
            float d  = __fsub_rn(A0, __fadd_rn(c0, c0));
            int   bj = jcol;
            const float d1 = __fsub_rn(A1, __fadd_rn(c1, c1));
            if (d1 < d) { d = d1; bj = jcol + 1; }            // jcol < jcol+1: tie keeps jcol
            #pragma unroll
            for (int o = 1; o < 64; o <<= 1) {                // argmin, first-index ties
                const float od = __shfl_xor(d, o, 64);
                const int   oj = __shfl_xor(bj, o, 64);
                if (od < d || (od == d && oj < bj)) { d = od; bj = oj; }
            }
            if (lane == 0) {
                const unsigned long long key =
                    ((unsigned long long)__float_as_uint(d) << 32) | (unsigned int)bj;
                atomicMin(packed + rows[it], key);   // d>0 -> monotone; deterministic
            }
        }
    }
}

// ---------- phase 3: z_q + idx from packed ----------
__global__ __launch_bounds__(256)
void vq_zq(const float* __restrict__ z, const float* __restrict__ e,
           const unsigned long long* __restrict__ packed, float* __restrict__ out)
{
    const size_t m = (size_t)blockIdx.x * 256 + threadIdx.x;
    const int r = (int)(m >> 6), k = (int)(m & 63);
    const int sel = (int)(packed[r] & 0xFFFFFFFFull);
    const float zv = z[m];
    const float ev = e[(size_t)sel * D + k];
    out[m] = __fadd_rn(zv, __fsub_rn(ev, zv));
    if (k == 0) out[(size_t)NROWS * D + r] = (float)sel;
}

extern "C" void kernel_launch(void* const* d_in, const int* in_sizes, int n_in,
                              void* d_out, int out_size, void* d_ws, size_t ws_size,
                              hipStream_t stream)
{
    const float* z = (const float*)d_in[0];
    const float* e = (const float*)d_in[1];
    float* out = (float*)d_out;

    char* ws = (char*)d_ws;
    const size_t MB = 1024 * 1024, KB = 1024;
    uint16_t* zb               = (uint16_t*)(ws);                         // 0..2 MB
    uint16_t* eb               = (uint16_t*)(ws + 2 * MB);                // 2..3 MB
    float* cmaxb               = (float*)(ws + 3 * MB);                   // 3..7 MB
    float* sz_arr              = (float*)(ws + 7 * MB);                   // 64 KB
    float* se_arr              = (float*)(ws + 7 * MB + 64 * KB);         // 32 KB
    unsigned long long* mask   = (unsigned long long*)(ws + 7 * MB + 128 * KB); // 128 KB
    unsigned long long* packed = (unsigned long long*)(ws + 7 * MB + 256 * KB); // 128 KB
    unsigned int* counts       = (unsigned int*)(ws + 7 * MB + 384 * KB); // 256 B
    float* e_t                 = (float*)(ws + 8 * MB);                   // 8..10 MB
    int* cand                  = (int*)(ws + 12 * MB);                    // 4 MB

    vq_convert_prep<<<dim3(1536),            dim3(256), 0, stream>>>(z, e, (uint32_t*)zb, (uint32_t*)eb, sz_arr, se_arr);
    vq_transpose   <<<dim3(NE / 64),         dim3(256), 0, stream>>>(e, e_t);
    vq_scan_mfma   <<<dim3(4096),            dim3(256), 0, stream>>>(zb, eb, cmaxb);
    vq_select_mask <<<dim3(NROWS / 4),       dim3(256), 0, stream>>>(cmaxb, mask, packed);
    vq_compact     <<<dim3(NCH),             dim3(256), 0, stream>>>(mask, cand, counts);
    vq_eval        <<<dim3(NCH, EVG),        dim3(256), 0, stream>>>(z, e_t, sz_arr, se_arr, counts, cand, packed);
    vq_zq          <<<dim3(NROWS * D / 256), dim3(256), 0, stream>>>(z, e, packed, out);
}

// Round 24
// 83.400 us; speedup vs baseline: 1.5164x; 1.5164x over previous
//
#include <hip/hip_runtime.h>
#include <stdint.h>

// VectorQuantizer — f32 I/O confirmed. d_in[0]=z [16384,64], d_in[1]=e [8192,64];
// d_out f32: [z_q 16384*64][idx-as-float 16384]. d_ws = 256MB confirmed.
//
// FROZEN exact numerics (fixup path only):
//   sz,se: scalar pairwise-8; c: 4 lanes (k mod 4), mul/add separately rounded,
//   16-chunks ascending, reversed sub-blocks (+12,+8,+4,+0), hadd (q0+q1)+(q2+q3);
//   A=fl(sz+se); d=fl(A-2c); argmin strict-<, first (smallest) index wins.
//
// Round-24: the item-loop eval paradigm (10 variants, 39-55us floor) is DELETED.
// New: scan (r22-verified) -> rowmax (global max of c_bf16 per row) -> RESCAN
// (dense 64x64 grid, MFMA bit-identical to scan, threshold acc >= rmax-BAND =
// r21-validated capture bound; ~25-30K hits compacted via LDS atomics into
// per-block lists — no global atomics [r10], no divergent heavy bodies [r21
// failure]) -> FIXUP (wave per list, lane per hit, frozen exact d + verified
// atomicMin((d_bits<<32)|j)). Every row self-hits (its max is >= rmax-BAND).

#define NROWS 16384
#define NE    8192
#define D     64
#define BN    128
#define NCH   (NE / BN)     // 64
#define BAND  1.25e-4f
#define HCAP  256           // per-rescan-block hit capacity (E[hits]~7, Poisson)

typedef __attribute__((ext_vector_type(8))) short short8;
typedef __attribute__((ext_vector_type(4))) float f32x4;

__device__ __forceinline__ uint32_t bf16rn(float f) {
    union { float f; uint32_t u; } c; c.f = f;
    return (c.u + 0x7FFFu + ((c.u >> 16) & 1u)) >> 16;
}
__device__ __forceinline__ uint32_t pk2(float lo, float hi) {
    return bf16rn(lo) | (bf16rn(hi) << 16);
}

// ---------- phase 0: convert + exact prep + packed init ----------
__global__ __launch_bounds__(256)
void vq_convert_prep(const float* __restrict__ z, const float* __restrict__ e,
                     uint32_t* __restrict__ zb, uint32_t* __restrict__ eb,
                     float* __restrict__ sz_arr, float* __restrict__ se_arr,
                     unsigned long long* __restrict__ packed)
{
    if (blockIdx.x < 768) {
        const int i = blockIdx.x * 256 + threadIdx.x;
        const int nz = NROWS * D / 8;
        const int ne = NE * D / 8;
        if (i < nz) {
            const float4 a = ((const float4*)z)[i * 2];
            const float4 b = ((const float4*)z)[i * 2 + 1];
            uint4 o; o.x = pk2(a.x, a.y); o.y = pk2(a.z, a.w);
            o.z = pk2(b.x, b.y); o.w = pk2(b.z, b.w);
            ((uint4*)zb)[i] = o;
        } else if (i < nz + ne) {
            const int k = i - nz;
            const float4 a = ((const float4*)e)[k * 2];
            const float4 b = ((const float4*)e)[k * 2 + 1];
            uint4 o; o.x = pk2(a.x, a.y); o.y = pk2(a.z, a.w);
            o.z = pk2(b.x, b.y); o.w = pk2(b.z, b.w);
            ((uint4*)eb)[k] = o;
        }
    } else if (blockIdx.x < 1536) {
        const int pb   = blockIdx.x - 768;
        const int wave = threadIdx.x >> 6, lane = threadIdx.x & 63;
        const int g    = lane & 7;
        const int grow = pb * 32 + wave * 8 + (lane >> 3);
        const float* src = (grow < NROWS) ? z + (size_t)grow * D
                                          : e + (size_t)(grow - NROWS) * D;
        float acc = 0.f;
        #pragma unroll
        for (int i = 0; i < 8; ++i) {
            const float x = src[i * 8 + g];
            acc = __fadd_rn(acc, __fmul_rn(x, x));
        }
        const float s1 = __fadd_rn(acc, __shfl_xor(acc, 1, 64));
        const float s2 = __fadd_rn(s1,  __shfl_xor(s1, 2, 64));
        const float s4 = __fadd_rn(s2,  __shfl_xor(s2, 4, 64));
        if (g == 0) {
            if (grow < NROWS) sz_arr[grow] = s4;
            else              se_arr[grow - NROWS] = s4;
        }
    } else {   // blocks 1536..1599: packed init (64 x 256 = 16384)
        const int i = (blockIdx.x - 1536) * 256 + threadIdx.x;
        packed[i] = 0xFFFFFFFFFFFFFFFFull;
    }
}

// ---------- phase 1: scan (r22-verified) — one chunk/block, shfl-max ----------
__global__ __launch_bounds__(256)
void vq_scan_mfma(const uint16_t* __restrict__ zb, const uint16_t* __restrict__ eb,
                  float* __restrict__ cmax)
{
    __shared__ uint16_t elds[BN][72];

    const int tid  = threadIdx.x;
    const int lane = tid & 63, w = tid >> 6;
    const int mb   = blockIdx.x >> 6;
    const int ch   = blockIdx.x & 63;
    const int row0 = mb * 256 + w * 64;
    const int l15  = lane & 15, l4 = lane >> 4;

    {
        const int srow = tid >> 1, shalf = tid & 1;
        const uint16_t* sp = eb + (size_t)(ch * BN + srow) * D + shalf * 32;
        uint16_t* dp = &elds[srow][shalf * 32];
        #pragma unroll
        for (int q = 0; q < 4; ++q)
            *(short8*)(dp + q * 8) = *(const short8*)(sp + q * 8);
    }

    short8 af[4][2];
    #pragma unroll
    for (int m = 0; m < 4; ++m)
        #pragma unroll
        for (int h = 0; h < 2; ++h)
            af[m][h] = *(const short8*)(zb + (size_t)(row0 + m * 16 + l15) * D + h * 32 + l4 * 8);

    __syncthreads();

    const f32x4 z4 = {0.f, 0.f, 0.f, 0.f};
    f32x4 rm[4];
    #pragma unroll
    for (int m = 0; m < 4; ++m) rm[m] = {-3.0e38f, -3.0e38f, -3.0e38f, -3.0e38f};

    #pragma unroll 1
    for (int n = 0; n < 8; ++n) {
        const uint16_t* bp = &elds[n * 16 + l15][l4 * 8];
        const short8 b0 = *(const short8*)(bp);
        const short8 b1 = *(const short8*)(bp + 32);
        #pragma unroll
        for (int m = 0; m < 4; ++m) {
            f32x4 acc = __builtin_amdgcn_mfma_f32_16x16x32_bf16(af[m][0], b0, z4, 0, 0, 0);
            acc = __builtin_amdgcn_mfma_f32_16x16x32_bf16(af[m][1], b1, acc, 0, 0, 0);
            #pragma unroll
            for (int r = 0; r < 4; ++r) rm[m][r] = fmaxf(rm[m][r], acc[r]);
        }
    }

    #pragma unroll
    for (int m = 0; m < 4; ++m) {
        #pragma unroll
        for (int r = 0; r < 4; ++r) {
            #pragma unroll
            for (int o = 1; o < 16; o <<= 1)
                rm[m][r] = fmaxf(rm[m][r], __shfl_xor(rm[m][r], o, 64));
        }
        if (l15 < 4) {
            const float v = (l15 == 0) ? rm[m][0] : (l15 == 1) ? rm[m][1]
                          : (l15 == 2) ? rm[m][2] : rm[m][3];
            cmax[(size_t)(row0 + m * 16 + l4 * 4 + l15) * NCH + ch] = v;
        }
    }
}

// ---------- phase 2: per-row global max of c_bf16 ----------
__global__ __launch_bounds__(256)
void vq_rowmax(const float* __restrict__ cmax, float* __restrict__ rmax_arr)
{
    const int lane = threadIdx.x & 63, w = threadIdx.x >> 6;
    const int row = blockIdx.x * 4 + w;
    const float ci = cmax[(size_t)row * NCH + lane];
    float cm = ci;
    #pragma unroll
    for (int o = 1; o < 64; o <<= 1) cm = fmaxf(cm, __shfl_xor(cm, o, 64));
    if (lane == 0) rmax_arr[row] = cm;
}

// ---------- phase 3: dense rescan — bit-identical MFMA + hit compaction ----------
__global__ __launch_bounds__(256)
void vq_rescan(const uint16_t* __restrict__ zb, const uint16_t* __restrict__ eb,
               const float* __restrict__ rmax_arr,
               uint32_t* __restrict__ hits, uint32_t* __restrict__ hitcnt)
{
    __shared__ uint16_t elds[BN][72];
    __shared__ uint32_t hbuf[HCAP];
    __shared__ uint32_t hcnt;

    const int tid  = threadIdx.x;
    const int lane = tid & 63, w = tid >> 6;
    const int mb   = blockIdx.x >> 6;
    const int ch   = blockIdx.x & 63;
    const int row0 = mb * 256 + w * 64;
    const int l15  = lane & 15, l4 = lane >> 4;

    if (tid == 0) hcnt = 0;
    {
        const int srow = tid >> 1, shalf = tid & 1;
        const uint16_t* sp = eb + (size_t)(ch * BN + srow) * D + shalf * 32;
        uint16_t* dp = &elds[srow][shalf * 32];
        #pragma unroll
        for (int q = 0; q < 4; ++q)
            *(short8*)(dp + q * 8) = *(const short8*)(sp + q * 8);
    }

    short8 af[4][2];
    #pragma unroll
    for (int m = 0; m < 4; ++m)
        #pragma unroll
        for (int h = 0; h < 2; ++h)
            af[m][h] = *(const short8*)(zb + (size_t)(row0 + m * 16 + l15) * D + h * 32 + l4 * 8);

    // thresholds: row = row0 + m*16 + l4*4 + r (uniform across l15 -> L1 broadcast)
    float th[4][4];
    #pragma unroll
    for (int m = 0; m < 4; ++m)
        #pragma unroll
        for (int r = 0; r < 4; ++r)
            th[m][r] = rmax_arr[row0 + m * 16 + l4 * 4 + r] - BAND;

    __syncthreads();   // elds + hcnt ready

    const f32x4 z4 = {0.f, 0.f, 0.f, 0.f};
    #pragma unroll 1
    for (int n = 0; n < 8; ++n) {
        const uint16_t* bp = &elds[n * 16 + l15][l4 * 8];
        const short8 b0 = *(const short8*)(bp);
        const short8 b1 = *(const short8*)(bp + 32);
        const int jcol = ch * BN + n * 16 + l15;
        #pragma unroll
        for (int m = 0; m < 4; ++m) {
            f32x4 acc = __builtin_amdgcn_mfma_f32_16x16x32_bf16(af[m][0], b0, z4, 0, 0, 0);
            acc = __builtin_amdgcn_mfma_f32_16x16x32_bf16(af[m][1], b1, acc, 0, 0, 0);
            #pragma unroll
            for (int r = 0; r < 4; ++r) {
                if (acc[r] >= th[m][r]) {   // rare (~7/block): LDS atomic is cheap
                    const uint32_t row = (uint32_t)(row0 + m * 16 + l4 * 4 + r);
                    const uint32_t s = atomicAdd(&hcnt, 1u);
                    if (s < HCAP) hbuf[s] = (row << 13) | (uint32_t)jcol;
                }
            }
        }
    }
    __syncthreads();

    const uint32_t cnt = (hcnt < HCAP) ? hcnt : HCAP;
    for (uint32_t i = tid; i < cnt; i += 256)
        hits[(size_t)blockIdx.x * HCAP + i] = hbuf[i];
    if (tid == 0) hitcnt[blockIdx.x] = cnt;
}

// ---------- phase 4: fixup — wave per rescan-block list, lane per hit ----------
__global__ __launch_bounds__(256)
void vq_fixup(const float* __restrict__ z, const float* __restrict__ e,
              const float* __restrict__ sz_arr, const float* __restrict__ se_arr,
              const uint32_t* __restrict__ hits, const uint32_t* __restrict__ hitcnt,
              unsigned long long* __restrict__ packed)
{
    const int lane = threadIdx.x & 63, w = threadIdx.x >> 6;
    const int wid  = blockIdx.x * 4 + w;           // rescan block id 0..4095
    const uint32_t cnt = hitcnt[wid];

    for (uint32_t s = (uint32_t)lane; s < cnt; s += 64) {
        const uint32_t entry = hits[(size_t)wid * HCAP + s];
        const int row = (int)(entry >> 13);
        const int j   = (int)(entry & 0x1FFFu);
        const float* zp = z + (size_t)row * D;
        const float* ep = e + (size_t)j * D;

        // frozen order: cc ascending; granules +12,+8,+4,+0; q_i gets k===i mod 4
        float q0 = 0.f, q1 = 0.f, q2 = 0.f, q3 = 0.f;
        #pragma unroll
        for (int cc = 0; cc < 4; ++cc) {
            #pragma unroll
            for (int sb = 3; sb >= 0; --sb) {
                const int b = cc * 16 + sb * 4;
                const float4 zv = *(const float4*)(zp + b);
                const float4 ev = *(const float4*)(ep + b);
                q0 = __fadd_rn(q0, __fmul_rn(zv.x, ev.x));
                q1 = __fadd_rn(q1, __fmul_rn(zv.y, ev.y));
                q2 = __fadd_rn(q2, __fmul_rn(zv.z, ev.z));
                q3 = __fadd_rn(q3, __fmul_rn(zv.w, ev.w));
            }
        }
        const float c = __fadd_rn(__fadd_rn(q0, q1), __fadd_rn(q2, q3));
        const float A = __fadd_rn(sz_arr[row], se_arr[j]);   // fl(sz + se)
        const float d = __fsub_rn(A, __fadd_rn(c, c));        // fl(A - 2c)
        const unsigned long long key =
            ((unsigned long long)__float_as_uint(d) << 32) | (unsigned int)j;
        atomicMin(packed + row, key);   // d>0 -> monotone bits; order-invariant
    }
}

// ---------- phase 5: z_q + idx from packed ----------
__global__ __launch_bounds__(256)
void vq_zq(const float* __restrict__ z, const float* __restrict__ e,
           const unsigned long long* __restrict__ packed, float* __restrict__ out)
{
    const size_t m = (size_t)blockIdx.x * 256 + threadIdx.x;
    const int r = (int)(m >> 6), k = (int)(m & 63);
    const int sel = (int)(packed[r] & 0xFFFFFFFFull);
    const float zv = z[m];
    const float ev = e[(size_t)sel * D + k];
    out[m] = __fadd_rn(zv, __fsub_rn(ev, zv));
    if (k == 0) out[(size_t)NROWS * D + r] = (float)sel;
}

extern "C" void kernel_launch(void* const* d_in, const int* in_sizes, int n_in,
                              void* d_out, int out_size, void* d_ws, size_t ws_size,
                              hipStream_t stream)
{
    const float* z = (const float*)d_in[0];
    const float* e = (const float*)d_in[1];
    float* out = (float*)d_out;

    char* ws = (char*)d_ws;
    const size_t MB = 1024 * 1024, KB = 1024;
    uint16_t* zb               = (uint16_t*)(ws);                         // 0..2 MB
    uint16_t* eb               = (uint16_t*)(ws + 2 * MB);                // 2..3 MB
    float* cmaxb               = (float*)(ws + 3 * MB);                   // 3..7 MB
    float* sz_arr              = (float*)(ws + 7 * MB);                   // 64 KB
    float* se_arr              = (float*)(ws + 7 * MB + 64 * KB);         // 32 KB
    float* rmax_arr            = (float*)(ws + 7 * MB + 128 * KB);        // 64 KB
    unsigned long long* packed = (unsigned long long*)(ws + 7 * MB + 256 * KB); // 128 KB
    uint32_t* hitcnt           = (uint32_t*)(ws + 7 * MB + 512 * KB);     // 16 KB
    uint32_t* hits             = (uint32_t*)(ws + 8 * MB);                // 4 MB (4096*256*4B)

    vq_convert_prep<<<dim3(1600),            dim3(256), 0, stream>>>(z, e, (uint32_t*)zb, (uint32_t*)eb, sz_arr, se_arr, packed);
    vq_scan_mfma   <<<dim3(4096),            dim3(256), 0, stream>>>(zb, eb, cmaxb);
    vq_rowmax      <<<dim3(NROWS / 4),       dim3(256), 0, stream>>>(cmaxb, rmax_arr);
    vq_rescan      <<<dim3(4096),            dim3(256), 0, stream>>>(zb, eb, rmax_arr, hits, hitcnt);
    vq_fixup       <<<dim3(1024),            dim3(256), 0, stream>>>(z, e, sz_arr, se_arr, hits, hitcnt, packed);
    vq_zq          <<<dim3(NROWS * D / 256), dim3(256), 0, stream>>>(z, e, packed, out);
}